// Round 1
// baseline (1210.884 us; speedup 1.0000x reference)
//
#include <hip/hip_runtime.h>

typedef __bf16 bf16x8 __attribute__((ext_vector_type(8)));
typedef float f32x4 __attribute__((ext_vector_type(4)));

#define MFMA(a, b, c) __builtin_amdgcn_mfma_f32_16x16x32_bf16((a), (b), (c), 0, 0, 0)

static constexpr int SEQ = 4096;
static constexpr int DIM = 512;

// ---------------------------------------------------------------------------
// GEMM: C[M][N] = A[M][K] @ B[N][K]^T   (B given in B^T layout, row n contig k)
// 64x64 tile, BK=32, 256 threads = 4 waves, each wave 32x32 via 2x2 mfma 16x16x32
// ---------------------------------------------------------------------------
template <bool A_F32, bool B_F32, bool OUT_BF16, bool BIAS>
__global__ __launch_bounds__(256, 2)
void gemm_bt(const void* __restrict__ Ap, const void* __restrict__ Bp,
             void* __restrict__ Cp, const float* __restrict__ bias,
             int M, int N, int K)
{
    __shared__ __bf16 As[64][40];  // +8 bf16 pad -> 2-way bank aliasing (free)
    __shared__ __bf16 Bs[64][40];
    const int tid  = threadIdx.x;
    const int wave = tid >> 6;
    const int lane = tid & 63;
    const int quad = lane >> 4;
    const int l16  = lane & 15;
    const int m0 = blockIdx.x * 64;
    const int n0 = blockIdx.y * 64;
    const int wm = (wave >> 1) * 32;
    const int wn = (wave & 1) * 32;
    const int lr = tid >> 2;        // staging row 0..63
    const int lc = (tid & 3) * 8;   // staging col 0..24

    f32x4 acc[2][2] = {};

    for (int k0 = 0; k0 < K; k0 += 32) {
        bf16x8 va, vb;
        if (A_F32) {
            const float* p = (const float*)Ap + (size_t)(m0 + lr) * K + k0 + lc;
            float4 f0 = *(const float4*)p;
            float4 f1 = *(const float4*)(p + 4);
            va[0] = (__bf16)f0.x; va[1] = (__bf16)f0.y; va[2] = (__bf16)f0.z; va[3] = (__bf16)f0.w;
            va[4] = (__bf16)f1.x; va[5] = (__bf16)f1.y; va[6] = (__bf16)f1.z; va[7] = (__bf16)f1.w;
        } else {
            va = *(const bf16x8*)((const __bf16*)Ap + (size_t)(m0 + lr) * K + k0 + lc);
        }
        if (B_F32) {
            const float* p = (const float*)Bp + (size_t)(n0 + lr) * K + k0 + lc;
            float4 f0 = *(const float4*)p;
            float4 f1 = *(const float4*)(p + 4);
            vb[0] = (__bf16)f0.x; vb[1] = (__bf16)f0.y; vb[2] = (__bf16)f0.z; vb[3] = (__bf16)f0.w;
            vb[4] = (__bf16)f1.x; vb[5] = (__bf16)f1.y; vb[6] = (__bf16)f1.z; vb[7] = (__bf16)f1.w;
        } else {
            vb = *(const bf16x8*)((const __bf16*)Bp + (size_t)(n0 + lr) * K + k0 + lc);
        }
        *(bf16x8*)&As[lr][lc] = va;
        *(bf16x8*)&Bs[lr][lc] = vb;
        __syncthreads();
        bf16x8 a0 = *(const bf16x8*)&As[wm + l16][quad * 8];
        bf16x8 a1 = *(const bf16x8*)&As[wm + 16 + l16][quad * 8];
        bf16x8 b0 = *(const bf16x8*)&Bs[wn + l16][quad * 8];
        bf16x8 b1 = *(const bf16x8*)&Bs[wn + 16 + l16][quad * 8];
        acc[0][0] = MFMA(a0, b0, acc[0][0]);
        acc[0][1] = MFMA(a0, b1, acc[0][1]);
        acc[1][0] = MFMA(a1, b0, acc[1][0]);
        acc[1][1] = MFMA(a1, b1, acc[1][1]);
        __syncthreads();
    }
    // C/D layout: col = lane&15, row = quad*4 + reg
    #pragma unroll
    for (int i = 0; i < 2; i++)
        #pragma unroll
        for (int jj = 0; jj < 2; jj++)
            #pragma unroll
            for (int r = 0; r < 4; r++) {
                int row = m0 + wm + i * 16 + quad * 4 + r;
                int col = n0 + wn + jj * 16 + l16;
                float v = acc[i][jj][r];
                if (BIAS) v += bias[col];
                if (OUT_BF16) ((__bf16*)Cp)[(size_t)row * N + col] = (__bf16)v;
                else          ((float*)Cp)[(size_t)row * N + col] = v;
            }
}

// ---------------------------------------------------------------------------
// Transpose [4][SEQ][DIM] bf16 -> [4][DIM][SEQ] (for contiguous PV B-fragments)
// ---------------------------------------------------------------------------
__global__ __launch_bounds__(256)
void transpose_bf16(const __bf16* __restrict__ in, __bf16* __restrict__ out)
{
    __shared__ __bf16 T[64][72];
    const int nb = blockIdx.z;
    const int s0 = blockIdx.x * 64;
    const int d0 = blockIdx.y * 64;
    const int t = threadIdx.x;
    const int r = t >> 3;          // 0..31
    const int c = (t & 7) * 8;     // 0..56
    const __bf16* src = in + (size_t)nb * SEQ * DIM;
    __bf16* dst = out + (size_t)nb * DIM * SEQ;
    #pragma unroll
    for (int rr = 0; rr < 64; rr += 32) {
        bf16x8 v = *(const bf16x8*)(src + (size_t)(s0 + r + rr) * DIM + d0 + c);
        *(bf16x8*)&T[r + rr][c] = v;
    }
    __syncthreads();
    #pragma unroll
    for (int rr = 0; rr < 64; rr += 32) {
        bf16x8 v;
        #pragma unroll
        for (int i = 0; i < 8; i++) v[i] = T[c + i][r + rr];
        *(bf16x8*)(dst + (size_t)(d0 + r + rr) * SEQ + s0 + c) = v;
    }
}

// ---------------------------------------------------------------------------
// Flash attention: BM=32 q-rows per block, BN=64 k-cols per iter, 64 iters.
// Wave w: score cols [16w,16w+16); O accumulator d-slice [128w, 128w+128).
// ---------------------------------------------------------------------------
__global__ __launch_bounds__(256, 2)
void flash_attn(const __bf16* __restrict__ Qp, const __bf16* __restrict__ Kp,
                const __bf16* __restrict__ Vt, const int* __restrict__ mask,
                __bf16* __restrict__ AO)
{
    constexpr float SCALE   = 0.044194173824159216f;   // 1/sqrt(512)
    constexpr float MASKEDV = -1e20f * 0.044194173824159216f;
    const int n  = blockIdx.y;
    const int q0 = blockIdx.x * 32;
    const int tid  = threadIdx.x;
    const int wave = tid >> 6;
    const int lane = tid & 63;
    const int quad = lane >> 4;
    const int l16  = lane & 15;
    const int sr = tid >> 3;        // softmax row 0..31
    const int sc = (tid & 7) * 8;   // softmax col group

    __shared__ float  Sc[32][65];
    __shared__ __bf16 P[32][72];
    __shared__ float  m_s[32], l_s[32], alpha_s[32];

    if (tid < 32) { m_s[tid] = -__builtin_inff(); l_s[tid] = 0.f; }

    f32x4 o[2][8] = {};

    const __bf16* Qb = Qp + (size_t)n * SEQ * DIM;
    const __bf16* Kb = Kp + (size_t)n * SEQ * DIM;
    const __bf16* Vb = Vt + (size_t)n * DIM * SEQ;
    const int*    Mb = mask + (size_t)n * SEQ * SEQ;

    const __bf16* qrow0 = Qb + (size_t)(q0 + l16) * DIM + quad * 8;
    const __bf16* qrow1 = qrow0 + 16 * DIM;

    for (int j = 0; j < 64; j++) {
        const int k0 = j * 64;
        // ---- phase 1: scores (this wave's 16-col strip), K inner = 512
        f32x4 s0 = {}, s1 = {};
        const __bf16* krow = Kb + (size_t)(k0 + wave * 16 + l16) * DIM + quad * 8;
        #pragma unroll
        for (int kk = 0; kk < 16; kk++) {
            bf16x8 a0 = *(const bf16x8*)(qrow0 + kk * 32);
            bf16x8 a1 = *(const bf16x8*)(qrow1 + kk * 32);
            bf16x8 b  = *(const bf16x8*)(krow + kk * 32);
            s0 = MFMA(a0, b, s0);
            s1 = MFMA(a1, b, s1);
        }
        #pragma unroll
        for (int i = 0; i < 4; i++) {
            Sc[quad * 4 + i][wave * 16 + l16]      = s0[i];
            Sc[16 + quad * 4 + i][wave * 16 + l16] = s1[i];
        }
        __syncthreads();
        // ---- phase 2: masked online softmax (8 threads per row)
        {
            const float m_old = m_s[sr];
            const int* mrow = Mb + (size_t)(q0 + sr) * SEQ + k0 + sc;
            int4 mk0 = *(const int4*)mrow;
            int4 mk1 = *(const int4*)(mrow + 4);
            const float* scr = &Sc[sr][sc];
            float vals[8];
            vals[0] = mk0.x ? scr[0] * SCALE : MASKEDV;
            vals[1] = mk0.y ? scr[1] * SCALE : MASKEDV;
            vals[2] = mk0.z ? scr[2] * SCALE : MASKEDV;
            vals[3] = mk0.w ? scr[3] * SCALE : MASKEDV;
            vals[4] = mk1.x ? scr[4] * SCALE : MASKEDV;
            vals[5] = mk1.y ? scr[5] * SCALE : MASKEDV;
            vals[6] = mk1.z ? scr[6] * SCALE : MASKEDV;
            vals[7] = mk1.w ? scr[7] * SCALE : MASKEDV;
            float mx = vals[0];
            #pragma unroll
            for (int i = 1; i < 8; i++) mx = fmaxf(mx, vals[i]);
            mx = fmaxf(mx, __shfl_xor(mx, 1));
            mx = fmaxf(mx, __shfl_xor(mx, 2));
            mx = fmaxf(mx, __shfl_xor(mx, 4));
            const float m_new = fmaxf(m_old, mx);
            float lsum = 0.f;
            bf16x8 pv;
            #pragma unroll
            for (int i = 0; i < 8; i++) {
                float p = __expf(vals[i] - m_new);
                lsum += p;
                pv[i] = (__bf16)p;
            }
            *(bf16x8*)&P[sr][sc] = pv;
            lsum += __shfl_xor(lsum, 1);
            lsum += __shfl_xor(lsum, 2);
            lsum += __shfl_xor(lsum, 4);
            if ((tid & 7) == 0) {
                const float alpha = __expf(m_old - m_new);
                m_s[sr]     = m_new;
                alpha_s[sr] = alpha;
                l_s[sr]     = l_s[sr] * alpha + lsum;
            }
        }
        __syncthreads();
        // ---- phase 3: rescale O, then O += P @ V (this wave's 128-d slice)
        float al0[4], al1[4];
        #pragma unroll
        for (int i = 0; i < 4; i++) {
            al0[i] = alpha_s[quad * 4 + i];
            al1[i] = alpha_s[16 + quad * 4 + i];
        }
        #pragma unroll
        for (int dt = 0; dt < 8; dt++)
            #pragma unroll
            for (int i = 0; i < 4; i++) {
                o[0][dt][i] *= al0[i];
                o[1][dt][i] *= al1[i];
            }
        #pragma unroll
        for (int ks = 0; ks < 2; ks++) {
            bf16x8 a0 = *(const bf16x8*)&P[l16][ks * 32 + quad * 8];
            bf16x8 a1 = *(const bf16x8*)&P[16 + l16][ks * 32 + quad * 8];
            #pragma unroll
            for (int dt = 0; dt < 8; dt++) {
                const __bf16* vp = Vb + (size_t)(wave * 128 + dt * 16 + l16) * SEQ
                                   + k0 + ks * 32 + quad * 8;
                bf16x8 b = *(const bf16x8*)vp;
                o[0][dt] = MFMA(a0, b, o[0][dt]);
                o[1][dt] = MFMA(a1, b, o[1][dt]);
            }
        }
    }
    __syncthreads();
    float li0[4], li1[4];
    #pragma unroll
    for (int i = 0; i < 4; i++) {
        li0[i] = 1.f / l_s[quad * 4 + i];
        li1[i] = 1.f / l_s[16 + quad * 4 + i];
    }
    #pragma unroll
    for (int dt = 0; dt < 8; dt++)
        #pragma unroll
        for (int i = 0; i < 4; i++) {
            AO[(size_t)(n * SEQ + q0 + quad * 4 + i) * DIM + wave * 128 + dt * 16 + l16]
                = (__bf16)(o[0][dt][i] * li0[i]);
            AO[(size_t)(n * SEQ + q0 + 16 + quad * 4 + i) * DIM + wave * 128 + dt * 16 + l16]
                = (__bf16)(o[1][dt][i] * li1[i]);
        }
}

// ---------------------------------------------------------------------------
extern "C" void kernel_launch(void* const* d_in, const int* in_sizes, int n_in,
                              void* d_out, int out_size, void* d_ws, size_t ws_size,
                              hipStream_t stream)
{
    const float* values = (const float*)d_in[0];
    const float* keys   = (const float*)d_in[1];
    const float* query  = (const float*)d_in[2];
    const int*   mask   = (const int*)d_in[3];
    const float* Wv = (const float*)d_in[4];
    const float* Wk = (const float*)d_in[5];
    const float* Wq = (const float*)d_in[6];
    const float* Wo = (const float*)d_in[7];
    const float* bo = (const float*)d_in[8];
    float* out = (float*)d_out;

    char* ws = (char*)d_ws;
    __bf16* Qp = (__bf16*)(ws);                       // 16 MiB
    __bf16* Kp = (__bf16*)(ws + (16u << 20));         // 16 MiB
    __bf16* Vp = (__bf16*)(ws + (32u << 20));         // 16 MiB (reused as AO)
    __bf16* Vt = (__bf16*)(ws + (48u << 20));         // 16 MiB
    __bf16* AO = Vp;   // Vp is dead after the transpose; flash writes AO here

    const int M = 4 * SEQ;  // 16384
    dim3 gproj(M / 64, DIM / 64);
    gemm_bt<true, true, true, false><<<gproj, 256, 0, stream>>>(query,  Wq, Qp, nullptr, M, DIM, DIM);
    gemm_bt<true, true, true, false><<<gproj, 256, 0, stream>>>(keys,   Wk, Kp, nullptr, M, DIM, DIM);
    gemm_bt<true, true, true, false><<<gproj, 256, 0, stream>>>(values, Wv, Vp, nullptr, M, DIM, DIM);

    dim3 gtr(SEQ / 64, DIM / 64, 4);
    transpose_bf16<<<gtr, 256, 0, stream>>>(Vp, Vt);

    dim3 gfa(SEQ / 32, 4);
    flash_attn<<<gfa, 256, 0, stream>>>(Qp, Kp, Vt, mask, AO);

    gemm_bt<false, true, false, true><<<gproj, 256, 0, stream>>>(AO, Wo, out, bo, M, DIM, DIM);
}

// Round 2
// 957.996 us; speedup vs baseline: 1.2640x; 1.2640x over previous
//
#include <hip/hip_runtime.h>

typedef __bf16 bf16x8 __attribute__((ext_vector_type(8)));
typedef float f32x4 __attribute__((ext_vector_type(4)));

#define MFMA(a, b, c) __builtin_amdgcn_mfma_f32_16x16x32_bf16((a), (b), (c), 0, 0, 0)

static constexpr int SEQ = 4096;
static constexpr int DIM = 512;

__device__ __forceinline__ bf16x8 cvt8(const float* __restrict__ p) {
    float4 f0 = *(const float4*)p;
    float4 f1 = *(const float4*)(p + 4);
    bf16x8 v;
    v[0] = (__bf16)f0.x; v[1] = (__bf16)f0.y; v[2] = (__bf16)f0.z; v[3] = (__bf16)f0.w;
    v[4] = (__bf16)f1.x; v[5] = (__bf16)f1.y; v[6] = (__bf16)f1.z; v[7] = (__bf16)f1.w;
    return v;
}

// ---------------------------------------------------------------------------
// GEMM: C[M][N] = A[M][K] @ B[N][K]^T. 128x128 tile, BK=64, 256 thr = 4 waves,
// each wave 64x64 via 4x4 mfma 16x16x32. LDS chunks XOR-swizzled: logical 16B
// chunk (row, lc) stored at (row, lc ^ (row&7)) -> conflict-free b128 reads.
// ---------------------------------------------------------------------------
template <bool A_F32, bool B_F32, bool OUT_BF16, bool BIAS>
__global__ __launch_bounds__(256, 3)
void gemm128(const void* __restrict__ Ap, const void* __restrict__ Bp,
             void* __restrict__ Cp, const float* __restrict__ bias,
             int M, int N, int K)
{
    __shared__ __bf16 As[128 * 64];
    __shared__ __bf16 Bs[128 * 64];
    const int tid  = threadIdx.x;
    const int wave = tid >> 6;
    const int lane = tid & 63;
    const int quad = lane >> 4;
    const int l16  = lane & 15;
    const int m0 = blockIdx.x * 128;
    const int n0 = blockIdx.y * 128;
    const int wm = (wave >> 1) * 64;
    const int wn = (wave & 1) * 64;
    const int srow = tid >> 3;   // 0..31 (+32i)
    const int slc  = tid & 7;    // 16B chunk col 0..7

    f32x4 acc[4][4] = {};

    for (int k0 = 0; k0 < K; k0 += 64) {
        #pragma unroll
        for (int i = 0; i < 4; i++) {
            const int row = srow + 32 * i;
            const int pc  = slc ^ (row & 7);
            bf16x8 va, vb;
            if (A_F32) va = cvt8((const float*)Ap + (size_t)(m0 + row) * K + k0 + slc * 8);
            else       va = *(const bf16x8*)((const __bf16*)Ap + (size_t)(m0 + row) * K + k0 + slc * 8);
            if (B_F32) vb = cvt8((const float*)Bp + (size_t)(n0 + row) * K + k0 + slc * 8);
            else       vb = *(const bf16x8*)((const __bf16*)Bp + (size_t)(n0 + row) * K + k0 + slc * 8);
            *(bf16x8*)&As[row * 64 + pc * 8] = va;
            *(bf16x8*)&Bs[row * 64 + pc * 8] = vb;
        }
        __syncthreads();
        #pragma unroll
        for (int kk = 0; kk < 2; kk++) {
            bf16x8 af[4], bg[4];
            #pragma unroll
            for (int mt = 0; mt < 4; mt++) {
                const int r = wm + mt * 16 + l16;
                af[mt] = *(const bf16x8*)&As[r * 64 + ((kk * 4 + quad) ^ (r & 7)) * 8];
            }
            #pragma unroll
            for (int nt = 0; nt < 4; nt++) {
                const int r = wn + nt * 16 + l16;
                bg[nt] = *(const bf16x8*)&Bs[r * 64 + ((kk * 4 + quad) ^ (r & 7)) * 8];
            }
            #pragma unroll
            for (int mt = 0; mt < 4; mt++)
                #pragma unroll
                for (int nt = 0; nt < 4; nt++)
                    acc[mt][nt] = MFMA(af[mt], bg[nt], acc[mt][nt]);
        }
        __syncthreads();
    }
    // C/D layout: col = lane&15, row = quad*4 + reg
    #pragma unroll
    for (int mt = 0; mt < 4; mt++)
        #pragma unroll
        for (int nt = 0; nt < 4; nt++)
            #pragma unroll
            for (int r = 0; r < 4; r++) {
                const int row = m0 + wm + mt * 16 + quad * 4 + r;
                const int col = n0 + wn + nt * 16 + l16;
                float v = acc[mt][nt][r];
                if (BIAS) v += bias[col];
                if (OUT_BF16) ((__bf16*)Cp)[(size_t)row * N + col] = (__bf16)v;
                else          ((float*)Cp)[(size_t)row * N + col] = v;
            }
}

// ---------------------------------------------------------------------------
// Transpose [4][SEQ][DIM] bf16 -> [4][DIM][SEQ]
// ---------------------------------------------------------------------------
__global__ __launch_bounds__(256)
void transpose_bf16(const __bf16* __restrict__ in, __bf16* __restrict__ out)
{
    __shared__ __bf16 T[64][72];
    const int nb = blockIdx.z;
    const int s0 = blockIdx.x * 64;
    const int d0 = blockIdx.y * 64;
    const int t = threadIdx.x;
    const int r = t >> 3;
    const int c = (t & 7) * 8;
    const __bf16* src = in + (size_t)nb * SEQ * DIM;
    __bf16* dst = out + (size_t)nb * DIM * SEQ;
    #pragma unroll
    for (int rr = 0; rr < 64; rr += 32) {
        bf16x8 v = *(const bf16x8*)(src + (size_t)(s0 + r + rr) * DIM + d0 + c);
        *(bf16x8*)&T[r + rr][c] = v;
    }
    __syncthreads();
    #pragma unroll
    for (int rr = 0; rr < 64; rr += 32) {
        bf16x8 v;
        #pragma unroll
        for (int i = 0; i < 8; i++) v[i] = T[c + i][r + rr];
        *(bf16x8*)(dst + (size_t)(d0 + r + rr) * SEQ + s0 + c) = v;
    }
}

// ---------------------------------------------------------------------------
// Flash attention v2: 512 threads (8 waves), BM=32 q-rows, BN=128 k-cols/iter.
// Q tile staged once in LDS (swizzled). Wave w: score cols [16w,16w+16),
// PV d-slice [64w, 64w+64). Mask prefetched at iteration top (hides HBM lat).
// ---------------------------------------------------------------------------
__global__ __launch_bounds__(512, 4)
void flash_attn(const __bf16* __restrict__ Qp, const __bf16* __restrict__ Kp,
                const __bf16* __restrict__ Vt, const int* __restrict__ mask,
                __bf16* __restrict__ AO)
{
    constexpr float SCALE   = 0.044194173824159216f;      // 1/sqrt(512)
    constexpr float MASKEDV = -1e20f * 0.044194173824159216f;

    __shared__ __bf16 Qs[32 * 512];      // 32 KB, 16B-chunk swizzled
    __shared__ float  Sc[32][132];       // 16.5 KB
    __shared__ __bf16 P[32 * 128];       // 8 KB, swizzled
    __shared__ float  m_s[32], l_s[32], alpha_s[32];

    const int n  = blockIdx.y;
    const int q0 = blockIdx.x * 32;
    const int tid  = threadIdx.x;
    const int wave = tid >> 6;
    const int lane = tid & 63;
    const int quad = lane >> 4;
    const int l16  = lane & 15;
    const int sr  = tid >> 4;        // softmax row 0..31
    const int scg = (tid & 15) * 8;  // softmax col group

    const __bf16* Qb = Qp + (size_t)n * SEQ * DIM;
    const __bf16* Kb = Kp + (size_t)n * SEQ * DIM;
    const __bf16* Vb = Vt + (size_t)n * DIM * SEQ;
    const int*    Mb = mask + (size_t)n * SEQ * SEQ;

    // ---- stage Q once (2048 16B chunks, 4 per thread)
    #pragma unroll
    for (int i = 0; i < 4; i++) {
        const int c   = i * 512 + tid;
        const int row = c >> 6;
        const int lc  = c & 63;
        const int pc  = (lc & 56) | ((lc & 7) ^ (row & 7));
        *(bf16x8*)&Qs[row * 512 + pc * 8] =
            *(const bf16x8*)(Qb + (size_t)(q0 + row) * DIM + lc * 8);
    }
    if (tid < 32) { m_s[tid] = -__builtin_inff(); l_s[tid] = 0.f; }
    __syncthreads();

    f32x4 o[2][4] = {};

    for (int j = 0; j < 32; j++) {
        const int k0 = j * 128;
        // ---- mask prefetch (HBM ~900cyc; overlapped by phase-1 MFMAs)
        const int* mrow = Mb + (size_t)(q0 + sr) * SEQ + k0 + scg;
        const int4 mk0 = *(const int4*)mrow;
        const int4 mk1 = *(const int4*)(mrow + 4);

        // ---- phase 1: scores, wave strip cols [16w,16w+16)
        f32x4 s0 = {}, s1 = {};
        const __bf16* krow = Kb + (size_t)(k0 + wave * 16 + l16) * DIM + quad * 8;
        #pragma unroll
        for (int kk = 0; kk < 16; kk++) {
            const int lc = kk * 4 + quad;
            const int r0 = l16, r1 = 16 + l16;
            bf16x8 a0 = *(const bf16x8*)&Qs[r0 * 512 + ((lc & 56) | ((lc & 7) ^ (r0 & 7))) * 8];
            bf16x8 a1 = *(const bf16x8*)&Qs[r1 * 512 + ((lc & 56) | ((lc & 7) ^ (r1 & 7))) * 8];
            bf16x8 b  = *(const bf16x8*)(krow + kk * 32);
            s0 = MFMA(a0, b, s0);
            s1 = MFMA(a1, b, s1);
        }
        #pragma unroll
        for (int i = 0; i < 4; i++) {
            Sc[quad * 4 + i][wave * 16 + l16]      = s0[i];
            Sc[16 + quad * 4 + i][wave * 16 + l16] = s1[i];
        }
        __syncthreads();

        // ---- phase 2: masked online softmax, 16 lanes per row
        {
            const float m_old = m_s[sr];
            const float4 sv0 = *(const float4*)&Sc[sr][scg];
            const float4 sv1 = *(const float4*)&Sc[sr][scg + 4];
            float vals[8];
            vals[0] = mk0.x ? sv0.x * SCALE : MASKEDV;
            vals[1] = mk0.y ? sv0.y * SCALE : MASKEDV;
            vals[2] = mk0.z ? sv0.z * SCALE : MASKEDV;
            vals[3] = mk0.w ? sv0.w * SCALE : MASKEDV;
            vals[4] = mk1.x ? sv1.x * SCALE : MASKEDV;
            vals[5] = mk1.y ? sv1.y * SCALE : MASKEDV;
            vals[6] = mk1.z ? sv1.z * SCALE : MASKEDV;
            vals[7] = mk1.w ? sv1.w * SCALE : MASKEDV;
            float mx = vals[0];
            #pragma unroll
            for (int i = 1; i < 8; i++) mx = fmaxf(mx, vals[i]);
            mx = fmaxf(mx, __shfl_xor(mx, 1));
            mx = fmaxf(mx, __shfl_xor(mx, 2));
            mx = fmaxf(mx, __shfl_xor(mx, 4));
            mx = fmaxf(mx, __shfl_xor(mx, 8));
            const float m_new = fmaxf(m_old, mx);
            float lsum = 0.f;
            bf16x8 pv;
            #pragma unroll
            for (int i = 0; i < 8; i++) {
                float p = __expf(vals[i] - m_new);
                lsum += p;
                pv[i] = (__bf16)p;
            }
            const int cc = tid & 15;
            const int pc = (cc & 8) | ((cc & 7) ^ (sr & 7));
            *(bf16x8*)&P[sr * 128 + pc * 8] = pv;
            lsum += __shfl_xor(lsum, 1);
            lsum += __shfl_xor(lsum, 2);
            lsum += __shfl_xor(lsum, 4);
            lsum += __shfl_xor(lsum, 8);
            if ((tid & 15) == 0) {
                const float alpha = __expf(m_old - m_new);
                m_s[sr]     = m_new;
                alpha_s[sr] = alpha;
                l_s[sr]     = l_s[sr] * alpha + lsum;
            }
        }
        __syncthreads();

        // ---- phase 3: rescale O, O += P @ V (wave d-slice [64w,64w+64))
        float al0[4], al1[4];
        #pragma unroll
        for (int i = 0; i < 4; i++) {
            al0[i] = alpha_s[quad * 4 + i];
            al1[i] = alpha_s[16 + quad * 4 + i];
        }
        #pragma unroll
        for (int dt = 0; dt < 4; dt++)
            #pragma unroll
            for (int i = 0; i < 4; i++) {
                o[0][dt][i] *= al0[i];
                o[1][dt][i] *= al1[i];
            }
        #pragma unroll
        for (int ks = 0; ks < 4; ks++) {
            const int lc = ks * 4 + quad;
            const int r0 = l16, r1 = 16 + l16;
            bf16x8 a0 = *(const bf16x8*)&P[r0 * 128 + ((lc & 8) | ((lc & 7) ^ (r0 & 7))) * 8];
            bf16x8 a1 = *(const bf16x8*)&P[r1 * 128 + ((lc & 8) | ((lc & 7) ^ (r1 & 7))) * 8];
            #pragma unroll
            for (int dt = 0; dt < 4; dt++) {
                const __bf16* vp = Vb + (size_t)(wave * 64 + dt * 16 + l16) * SEQ
                                   + k0 + ks * 32 + quad * 8;
                bf16x8 b = *(const bf16x8*)vp;
                o[0][dt] = MFMA(a0, b, o[0][dt]);
                o[1][dt] = MFMA(a1, b, o[1][dt]);
            }
        }
    }

    // ---- epilogue
    float li0[4], li1[4];
    #pragma unroll
    for (int i = 0; i < 4; i++) {
        li0[i] = 1.f / l_s[quad * 4 + i];
        li1[i] = 1.f / l_s[16 + quad * 4 + i];
    }
    #pragma unroll
    for (int dt = 0; dt < 4; dt++)
        #pragma unroll
        for (int i = 0; i < 4; i++) {
            AO[(size_t)(n * SEQ + q0 + quad * 4 + i) * DIM + wave * 64 + dt * 16 + l16]
                = (__bf16)(o[0][dt][i] * li0[i]);
            AO[(size_t)(n * SEQ + q0 + 16 + quad * 4 + i) * DIM + wave * 64 + dt * 16 + l16]
                = (__bf16)(o[1][dt][i] * li1[i]);
        }
}

// ---------------------------------------------------------------------------
extern "C" void kernel_launch(void* const* d_in, const int* in_sizes, int n_in,
                              void* d_out, int out_size, void* d_ws, size_t ws_size,
                              hipStream_t stream)
{
    const float* values = (const float*)d_in[0];
    const float* keys   = (const float*)d_in[1];
    const float* query  = (const float*)d_in[2];
    const int*   mask   = (const int*)d_in[3];
    const float* Wv = (const float*)d_in[4];
    const float* Wk = (const float*)d_in[5];
    const float* Wq = (const float*)d_in[6];
    const float* Wo = (const float*)d_in[7];
    const float* bo = (const float*)d_in[8];
    float* out = (float*)d_out;

    char* ws = (char*)d_ws;
    __bf16* Qp = (__bf16*)(ws);                 // 16 MiB
    __bf16* Kp = (__bf16*)(ws + (16u << 20));   // 16 MiB
    __bf16* Vp = (__bf16*)(ws + (32u << 20));   // 16 MiB (reused as AO)
    __bf16* Vt = (__bf16*)(ws + (48u << 20));   // 16 MiB
    __bf16* AO = Vp;

    const int M = 4 * SEQ;  // 16384
    dim3 gproj(M / 128, DIM / 128);
    gemm128<true, true, true, false><<<gproj, 256, 0, stream>>>(query,  Wq, Qp, nullptr, M, DIM, DIM);
    gemm128<true, true, true, false><<<gproj, 256, 0, stream>>>(keys,   Wk, Kp, nullptr, M, DIM, DIM);
    gemm128<true, true, true, false><<<gproj, 256, 0, stream>>>(values, Wv, Vp, nullptr, M, DIM, DIM);

    dim3 gtr(SEQ / 64, DIM / 64, 4);
    transpose_bf16<<<gtr, 256, 0, stream>>>(Vp, Vt);

    dim3 gfa(SEQ / 32, 4);
    flash_attn<<<gfa, 512, 0, stream>>>(Qp, Kp, Vt, mask, AO);

    gemm128<false, true, false, true><<<gproj, 256, 0, stream>>>(AO, Wo, out, bo, M, DIM, DIM);
}

// Round 3
// 836.315 us; speedup vs baseline: 1.4479x; 1.1455x over previous
//
#include <hip/hip_runtime.h>

typedef __bf16 bf16x8 __attribute__((ext_vector_type(8)));
typedef float f32x4 __attribute__((ext_vector_type(4)));

#define MFMA(a, b, c) __builtin_amdgcn_mfma_f32_16x16x32_bf16((a), (b), (c), 0, 0, 0)

static constexpr int SEQ = 4096;
static constexpr int DIM = 512;

__device__ __forceinline__ bf16x8 cvt8(const float* __restrict__ p) {
    float4 f0 = *(const float4*)p;
    float4 f1 = *(const float4*)(p + 4);
    bf16x8 v;
    v[0] = (__bf16)f0.x; v[1] = (__bf16)f0.y; v[2] = (__bf16)f0.z; v[3] = (__bf16)f0.w;
    v[4] = (__bf16)f1.x; v[5] = (__bf16)f1.y; v[6] = (__bf16)f1.z; v[7] = (__bf16)f1.w;
    return v;
}

// ---------------------------------------------------------------------------
// GEMM: C[M][N] = A[M][K] @ B[N][K]^T. 128x128 tile, BK=64, 4 waves x (64x64).
// launch_bounds (256,2): 256-VGPR cap -> no scratch spill (R2 theory: (256,3)
// capped at 170 VGPR and spilled).
// ---------------------------------------------------------------------------
template <bool QKV, bool A_F32, bool OUT_BF16, bool BIAS>
__global__ __launch_bounds__(256, 2)
void gemm128(const void* __restrict__ A0, const void* __restrict__ A1,
             const void* __restrict__ A2, const float* __restrict__ B0,
             const float* __restrict__ B1, const float* __restrict__ B2,
             void* __restrict__ C0, void* __restrict__ C1, void* __restrict__ C2,
             const float* __restrict__ bias, int M, int N, int K)
{
    const void* Ap = A0;
    const float* Bp = B0;
    void* Cp = C0;
    if (QKV) {
        const int z = blockIdx.z;
        Ap = (z == 0) ? A0 : (z == 1) ? A1 : A2;
        Bp = (z == 0) ? B0 : (z == 1) ? B1 : B2;
        Cp = (z == 0) ? C0 : (z == 1) ? C1 : C2;
    }
    __shared__ __bf16 As[128 * 64];
    __shared__ __bf16 Bs[128 * 64];
    const int tid  = threadIdx.x;
    const int wave = tid >> 6;
    const int lane = tid & 63;
    const int quad = lane >> 4;
    const int l16  = lane & 15;
    const int m0 = blockIdx.x * 128;
    const int n0 = blockIdx.y * 128;
    const int wm = (wave >> 1) * 64;
    const int wn = (wave & 1) * 64;
    const int srow = tid >> 3;   // 0..31 (+32i)
    const int slc  = tid & 7;    // 16B chunk col 0..7

    f32x4 acc[4][4] = {};

    for (int k0 = 0; k0 < K; k0 += 64) {
        #pragma unroll
        for (int i = 0; i < 4; i++) {
            const int row = srow + 32 * i;
            const int pc  = slc ^ (row & 7);
            bf16x8 va, vb;
            if (A_F32) va = cvt8((const float*)Ap + (size_t)(m0 + row) * K + k0 + slc * 8);
            else       va = *(const bf16x8*)((const __bf16*)Ap + (size_t)(m0 + row) * K + k0 + slc * 8);
            vb = cvt8(Bp + (size_t)(n0 + row) * K + k0 + slc * 8);
            *(bf16x8*)&As[row * 64 + pc * 8] = va;
            *(bf16x8*)&Bs[row * 64 + pc * 8] = vb;
        }
        __syncthreads();
        #pragma unroll
        for (int kk = 0; kk < 2; kk++) {
            bf16x8 af[4], bg[4];
            #pragma unroll
            for (int mt = 0; mt < 4; mt++) {
                const int r = wm + mt * 16 + l16;
                af[mt] = *(const bf16x8*)&As[r * 64 + ((kk * 4 + quad) ^ (r & 7)) * 8];
            }
            #pragma unroll
            for (int nt = 0; nt < 4; nt++) {
                const int r = wn + nt * 16 + l16;
                bg[nt] = *(const bf16x8*)&Bs[r * 64 + ((kk * 4 + quad) ^ (r & 7)) * 8];
            }
            #pragma unroll
            for (int mt = 0; mt < 4; mt++)
                #pragma unroll
                for (int nt = 0; nt < 4; nt++)
                    acc[mt][nt] = MFMA(af[mt], bg[nt], acc[mt][nt]);
        }
        __syncthreads();
    }
    #pragma unroll
    for (int mt = 0; mt < 4; mt++)
        #pragma unroll
        for (int nt = 0; nt < 4; nt++)
            #pragma unroll
            for (int r = 0; r < 4; r++) {
                const int row = m0 + wm + mt * 16 + quad * 4 + r;
                const int col = n0 + wn + nt * 16 + l16;
                float v = acc[mt][nt][r];
                if (BIAS) v += bias[col];
                if (OUT_BF16) ((__bf16*)Cp)[(size_t)row * N + col] = (__bf16)v;
                else          ((float*)Cp)[(size_t)row * N + col] = v;
            }
}

// ---------------------------------------------------------------------------
// Transpose [4][SEQ][DIM] bf16 -> [4][DIM][SEQ]
// ---------------------------------------------------------------------------
__global__ __launch_bounds__(256)
void transpose_bf16(const __bf16* __restrict__ in, __bf16* __restrict__ out)
{
    __shared__ __bf16 T[64][72];
    const int nb = blockIdx.z;
    const int s0 = blockIdx.x * 64;
    const int d0 = blockIdx.y * 64;
    const int t = threadIdx.x;
    const int r = t >> 3;
    const int c = (t & 7) * 8;
    const __bf16* src = in + (size_t)nb * SEQ * DIM;
    __bf16* dst = out + (size_t)nb * DIM * SEQ;
    #pragma unroll
    for (int rr = 0; rr < 64; rr += 32) {
        bf16x8 v = *(const bf16x8*)(src + (size_t)(s0 + r + rr) * DIM + d0 + c);
        *(bf16x8*)&T[r + rr][c] = v;
    }
    __syncthreads();
    #pragma unroll
    for (int rr = 0; rr < 64; rr += 32) {
        bf16x8 v;
        #pragma unroll
        for (int i = 0; i < 8; i++) v[i] = T[c + i][r + rr];
        *(bf16x8*)(dst + (size_t)(d0 + r + rr) * SEQ + s0 + c) = v;
    }
}

// ---------------------------------------------------------------------------
// Flash attention v3: 512 thr (8 waves), BM=64 q-rows/block, BN=256 k/iter,
// 16 iters. Q in LDS (staged once, swizzled). Per-wave: scores mt4 x nt2
// (cols 32*nw..+32), PV g4 x dt4 (d-slice 64*nw..+64). K/V from global,
// zero intra-block redundancy. Mask bit-packed to LDS. 3 barriers/iter.
// ---------------------------------------------------------------------------
__global__ __launch_bounds__(512, 2)
void flash_attn(const __bf16* __restrict__ Qp, const __bf16* __restrict__ Kp,
                const __bf16* __restrict__ Vt, const int* __restrict__ mask,
                __bf16* __restrict__ AO)
{
    constexpr float SCALE = 0.044194173824159216f;   // 1/sqrt(512)

    __shared__ __bf16 Qs[64 * 512];        // 64 KB, 16B-chunk swizzled
    __shared__ __bf16 P[64 * 256];         // 32 KB, swizzled
    __shared__ unsigned Wb[64 * 8];        // mask bits, 2 KB
    __shared__ float pmax[8][72];
    __shared__ float psum[8][72];
    __shared__ float m_s[2][64];
    __shared__ float alpha_s[64];
    __shared__ float l_s[64];
    __shared__ unsigned flag_s;

    const int n  = blockIdx.y;
    const int q0 = blockIdx.x * 64;
    const int tid  = threadIdx.x;
    const int nw   = tid >> 6;       // wave 0..7
    const int lane = tid & 63;
    const int quad = lane >> 4;
    const int l16  = lane & 15;

    const __bf16* Qb = Qp + (size_t)n * SEQ * DIM;
    const __bf16* Kb = Kp + (size_t)n * SEQ * DIM;
    const __bf16* Vb = Vt + (size_t)n * DIM * SEQ;
    const int*    Mb = mask + (size_t)n * SEQ * SEQ;

    // ---- stage Q once: 64 rows x 512, swizzled 16B chunks
    #pragma unroll
    for (int i = 0; i < 8; i++) {
        const int idx = i * 512 + tid;
        const int row = idx >> 6;
        const int lc  = idx & 63;
        const int pc  = (lc & 56) | ((lc & 7) ^ (row & 7));
        *(bf16x8*)&Qs[row * 512 + pc * 8] =
            *(const bf16x8*)(Qb + (size_t)(q0 + row) * DIM + lc * 8);
    }
    if (tid < 64) { m_s[0][tid] = -__builtin_inff(); l_s[tid] = 0.f; }
    __syncthreads();

    f32x4 o[4][4] = {};

    for (int j = 0; j < 16; j++) {
        const int k0 = j * 256;
        const int jp = j & 1;

        // ---- mask bit-pack (one u32 word per thread; read after barrier A2)
        {
            const int* mp = Mb + (size_t)(q0 + (tid >> 3)) * SEQ + k0 + (tid & 7) * 32;
            unsigned w = 0;
            #pragma unroll
            for (int c = 0; c < 8; c++) {
                int4 m4 = *(const int4*)(mp + c * 4);
                w |= (unsigned)(m4.x & 1) << (c * 4 + 0);
                w |= (unsigned)(m4.y & 1) << (c * 4 + 1);
                w |= (unsigned)(m4.z & 1) << (c * 4 + 2);
                w |= (unsigned)(m4.w & 1) << (c * 4 + 3);
            }
            Wb[tid] = w;
        }

        // ---- phase 1: scores. Wave nw -> cols [32nw, 32nw+32), rows all 64.
        f32x4 s[4][2] = {};
        {
            const __bf16* kb = Kb + (size_t)(k0 + nw * 32 + l16) * DIM + quad * 8;
            #pragma unroll
            for (int kk = 0; kk < 16; kk++) {
                bf16x8 b0 = *(const bf16x8*)(kb + kk * 32);
                bf16x8 b1 = *(const bf16x8*)(kb + 16 * DIM + kk * 32);
                const int lc = kk * 4 + quad;
                #pragma unroll
                for (int g = 0; g < 4; g++) {
                    const int row = g * 16 + l16;
                    bf16x8 a = *(const bf16x8*)&Qs[row * 512 + ((lc & 56) | ((lc & 7) ^ (row & 7))) * 8];
                    s[g][0] = MFMA(a, b0, s[g][0]);
                    s[g][1] = MFMA(a, b1, s[g][1]);
                }
            }
        }
        // ---- per-row partial max over this wave's 32 cols (RAW scores; mask
        //      applied after exp — shift-invariance makes this exact)
        #pragma unroll
        for (int g = 0; g < 4; g++) {
            f32x4 v;
            #pragma unroll
            for (int r = 0; r < 4; r++) v[r] = fmaxf(s[g][0][r], s[g][1][r]);
            #pragma unroll
            for (int d = 1; d < 16; d <<= 1) {
                #pragma unroll
                for (int r = 0; r < 4; r++) v[r] = fmaxf(v[r], __shfl_xor(v[r], d));
            }
            if (l16 == 0) {
                #pragma unroll
                for (int r = 0; r < 4; r++) pmax[nw][g * 16 + quad * 4 + r] = v[r];
            }
        }
        __syncthreads();   // A

        // ---- combine (threads 0..63, one row each)
        if (nw == 0) {
            float mp_ = pmax[0][lane];
            #pragma unroll
            for (int w2 = 1; w2 < 8; w2++) mp_ = fmaxf(mp_, pmax[w2][lane]);
            mp_ *= SCALE;
            const float mo = m_s[jp][lane];
            const float mn = fmaxf(mo, mp_);
            m_s[jp ^ 1][lane] = mn;
            alpha_s[lane] = __expf(mo - mn);
            unsigned long long ch = __ballot(mn > mo);
            if (lane == 0) flag_s = (unsigned)(ch | (ch >> 32));
        }
        __syncthreads();   // A2

        // ---- rescale O if any row max changed
        if (flag_s) {
            #pragma unroll
            for (int g = 0; g < 4; g++) {
                const float4 al = *(const float4*)&alpha_s[g * 16 + quad * 4];
                #pragma unroll
                for (int dt = 0; dt < 4; dt++)
                    #pragma unroll
                    for (int r = 0; r < 4; r++)
                        o[g][dt][r] *= ((const float*)&al)[r];
            }
        }
        // ---- exp, mask-zero, write P, psum partials
        const float* mnew = m_s[jp ^ 1];
        #pragma unroll
        for (int g = 0; g < 4; g++) {
            const float4 mn4 = *(const float4*)&mnew[g * 16 + quad * 4];
            f32x4 prow = {};
            #pragma unroll
            for (int r = 0; r < 4; r++) {
                const int row = g * 16 + quad * 4 + r;
                const unsigned wq = Wb[row * 8 + nw];
                #pragma unroll
                for (int nt = 0; nt < 2; nt++) {
                    float p = __expf(s[g][nt][r] * SCALE - ((const float*)&mn4)[r]);
                    p = ((wq >> (nt * 16 + l16)) & 1u) ? p : 0.f;
                    prow[r] += p;
                    const int col = nw * 32 + nt * 16 + l16;
                    const int ch2 = col >> 3;
                    const int pc  = (ch2 & 24) | ((ch2 & 7) ^ (row & 7));
                    P[row * 256 + pc * 8 + (col & 7)] = (__bf16)p;
                }
            }
            #pragma unroll
            for (int d = 1; d < 16; d <<= 1) {
                #pragma unroll
                for (int r = 0; r < 4; r++) prow[r] += __shfl_xor(prow[r], d);
            }
            if (l16 == 0) {
                #pragma unroll
                for (int r = 0; r < 4; r++) psum[nw][g * 16 + quad * 4 + r] = prow[r];
            }
        }
        __syncthreads();   // B

        // ---- l update (threads 0..63)
        if (nw == 0) {
            float acc = psum[0][lane];
            #pragma unroll
            for (int w2 = 1; w2 < 8; w2++) acc += psum[w2][lane];
            l_s[lane] = l_s[lane] * alpha_s[lane] + acc;
        }
        // ---- PV: wave nw -> d-slice [64nw, 64nw+64), rows all 64
        {
            const __bf16* vb = Vb + (size_t)(nw * 64 + l16) * SEQ + k0 + quad * 8;
            #pragma unroll
            for (int kk = 0; kk < 8; kk++) {
                bf16x8 pa[4];
                const int lc = kk * 4 + quad;
                #pragma unroll
                for (int g = 0; g < 4; g++) {
                    const int row = g * 16 + l16;
                    pa[g] = *(const bf16x8*)&P[row * 256 + ((lc & 24) | ((lc & 7) ^ (row & 7))) * 8];
                }
                #pragma unroll
                for (int dt = 0; dt < 4; dt++) {
                    bf16x8 b = *(const bf16x8*)(vb + (size_t)(dt * 16) * SEQ + kk * 32);
                    #pragma unroll
                    for (int g = 0; g < 4; g++)
                        o[g][dt] = MFMA(pa[g], b, o[g][dt]);
                }
            }
        }
    }

    __syncthreads();
    // ---- epilogue: O / l -> AO (bf16)
    #pragma unroll
    for (int g = 0; g < 4; g++) {
        const float4 l4 = *(const float4*)&l_s[g * 16 + quad * 4];
        float li[4];
        #pragma unroll
        for (int r = 0; r < 4; r++) li[r] = 1.f / ((const float*)&l4)[r];
        #pragma unroll
        for (int dt = 0; dt < 4; dt++)
            #pragma unroll
            for (int r = 0; r < 4; r++)
                AO[(size_t)(n * SEQ + q0 + g * 16 + quad * 4 + r) * DIM + nw * 64 + dt * 16 + l16]
                    = (__bf16)(o[g][dt][r] * li[r]);
    }
}

// ---------------------------------------------------------------------------
extern "C" void kernel_launch(void* const* d_in, const int* in_sizes, int n_in,
                              void* d_out, int out_size, void* d_ws, size_t ws_size,
                              hipStream_t stream)
{
    const float* values = (const float*)d_in[0];
    const float* keys   = (const float*)d_in[1];
    const float* query  = (const float*)d_in[2];
    const int*   mask   = (const int*)d_in[3];
    const float* Wv = (const float*)d_in[4];
    const float* Wk = (const float*)d_in[5];
    const float* Wq = (const float*)d_in[6];
    const float* Wo = (const float*)d_in[7];
    const float* bo = (const float*)d_in[8];
    float* out = (float*)d_out;

    char* ws = (char*)d_ws;
    __bf16* Qp = (__bf16*)(ws);                 // 16 MiB
    __bf16* Kp = (__bf16*)(ws + (16u << 20));   // 16 MiB
    __bf16* Vp = (__bf16*)(ws + (32u << 20));   // 16 MiB (reused as AO)
    __bf16* Vt = (__bf16*)(ws + (48u << 20));   // 16 MiB
    __bf16* AO = Vp;

    const int M = 4 * SEQ;  // 16384

    // fused Q/K/V projections (z selects input/weight/output)
    dim3 gproj(M / 128, DIM / 128, 3);
    gemm128<true, true, true, false><<<gproj, 256, 0, stream>>>(
        query, keys, values, Wq, Wk, Wv, Qp, Kp, Vp, nullptr, M, DIM, DIM);

    dim3 gtr(SEQ / 64, DIM / 64, 4);
    transpose_bf16<<<gtr, 256, 0, stream>>>(Vp, Vt);

    dim3 gfa(SEQ / 64, 4);
    flash_attn<<<gfa, 512, 0, stream>>>(Qp, Kp, Vt, mask, AO);

    dim3 gout(M / 128, DIM / 128, 1);
    gemm128<false, false, false, true><<<gout, 256, 0, stream>>>(
        AO, nullptr, nullptr, Wo, nullptr, nullptr, out, nullptr, nullptr, bo, M, DIM, DIM);
}